// Round 10
// baseline (492.149 us; speedup 1.0000x reference)
//
#include <hip/hip_runtime.h>

#define B_ 8
#define N_ 2048
#define K_ 30
#define H_ 128
#define LDA 136
#define EPS_ 1e-5f

typedef __attribute__((ext_vector_type(8))) short short8;
typedef __attribute__((ext_vector_type(4))) float f32x4;

// pack 2 f32 -> 2 bf16 (RNE) in one instr
__device__ inline unsigned pkbf(float lo, float hi) {
  unsigned r;
  asm("v_cvt_pk_bf16_f32 %0, %1, %2" : "=v"(r) : "v"(lo), "v"(hi));
  return r;
}

__device__ inline unsigned short f2bf(float f) { return (unsigned short)pkbf(f, f); }

__device__ inline float bf2f(unsigned short h) {
  union { unsigned u; float f; } v; v.u = ((unsigned)h) << 16; return v.f;
}

// tanh-form GELU with fast rcp
__device__ inline float gelu_t(float x) {
  const float p = x * x;
  const float z = x * (1.5957691216057308f + 0.07135481627f * p);
  const float e = exp2f(z * -1.4426950408889634f);  // e^{-z}
  return x * __builtin_amdgcn_rcpf(1.0f + e);
}

__device__ inline short8 pack8(float4 a, float4 b) {
  union { unsigned u[4]; short8 s; } v;
  v.u[0] = pkbf(a.x, a.y); v.u[1] = pkbf(a.z, a.w);
  v.u[2] = pkbf(b.x, b.y); v.u[3] = pkbf(b.z, b.w);
  return v.s;
}

// ---- swapped-operand GEMM: D[feature][edge] (k1) ----
template<int LDW>
__device__ inline void gemmT(const unsigned short* __restrict__ sA,
                             const unsigned short* __restrict__ W,
                             int lane, int cb, f32x4 (&acc)[4][2]) {
  const int rl = lane & 15;
  const int klo = (lane >> 4) << 3;
#pragma unroll
  for (int ks = 0; ks < 4; ++ks) {
    short8 wf[2];
#pragma unroll
    for (int fn = 0; fn < 2; ++fn)
      wf[fn] = *(const short8*)(W + (size_t)(cb + fn * 16 + rl) * LDW + ks * 32 + klo);
#pragma unroll
    for (int et = 0; et < 4; ++et) {
      const short8 ef = *(const short8*)(sA + (et * 16 + rl) * LDA + ks * 32 + klo);
      acc[et][0] = __builtin_amdgcn_mfma_f32_16x16x32_bf16(wf[0], ef, acc[et][0], 0, 0, 0);
      acc[et][1] = __builtin_amdgcn_mfma_f32_16x16x32_bf16(wf[1], ef, acc[et][1], 0, 0, 0);
    }
  }
}

#define ZERO42(A) \
  _Pragma("unroll") for (int e_ = 0; e_ < 4; ++e_) { A[e_][0] = (f32x4){0,0,0,0}; A[e_][1] = (f32x4){0,0,0,0}; }

// ---- old-layout 64-row wave GEMM (preY + k3): D[row][feature] ----
template<int LDW, int NN>
__device__ inline void gemm64(const unsigned short* __restrict__ sA,
                              const unsigned short* __restrict__ W,
                              int lane, int cb, f32x4 (&acc)[4][NN]) {
  const int rl = lane & 15;
  const int klo = (lane >> 4) << 3;
#pragma unroll
  for (int ks = 0; ks < 4; ++ks) {
    short8 a[4];
#pragma unroll
    for (int m = 0; m < 4; ++m)
      a[m] = *(const short8*)(sA + (m * 16 + rl) * LDA + ks * 32 + klo);
#pragma unroll
    for (int n = 0; n < NN; ++n) {
      const short8 b8 = *(const short8*)(W + (size_t)(cb + n * 16 + rl) * LDW + ks * 32 + klo);
#pragma unroll
      for (int m = 0; m < 4; ++m)
        acc[m][n] = __builtin_amdgcn_mfma_f32_16x16x32_bf16(a[m], b8, acc[m][n], 0, 0, 0);
    }
  }
}

// ---- prep: weights fp32 -> bf16 ----
__global__ __launch_bounds__(256) void prep(const float* __restrict__ w1, const float* __restrict__ w2,
                                            const float* __restrict__ w3, const float* __restrict__ w11,
                                            const float* __restrict__ w12, const float* __restrict__ w13,
                                            const float* __restrict__ din, const float* __restrict__ dout,
                                            unsigned short* __restrict__ dst) {
  const int i = blockIdx.x * 256 + threadIdx.x;  // grid covers exactly 294912
  const float* s; int off;
  if (i < 49152)       { s = w1;  off = 0; }
  else if (i < 65536)  { s = w2;  off = 49152; }
  else if (i < 81920)  { s = w3;  off = 65536; }
  else if (i < 131072) { s = w11; off = 81920; }
  else if (i < 147456) { s = w12; off = 131072; }
  else if (i < 163840) { s = w13; off = 147456; }
  else if (i < 229376) { s = din; off = 163840; }
  else                 { s = dout; off = 229376; }
  dst[i] = f2bf(s[i - off]);
}

// ---- pre-GEMM: Y = X @ [Wa|Wb]^T -> 256 cols (center|nbr halves) ----
template<bool F32SRC, bool SPLIT>
__global__ __launch_bounds__(256) void preY(const void* __restrict__ Xv,
                                            const unsigned short* __restrict__ Wbase,
                                            unsigned short* __restrict__ Yc,
                                            unsigned short* __restrict__ Yn) {
  __shared__ __align__(16) unsigned short sA[64 * LDA];
  const int tid = threadIdx.x;
  const int lane = tid & 63;
  const int w = tid >> 6;
  const int rows = blockIdx.x << 6;
  const int rl = lane & 15;
  const int h4 = (lane >> 4) << 2;

  if (F32SRC) {
    const float* X = (const float*)Xv;
    for (int t = tid; t < 1024; t += 256) {
      const int r = t >> 4, seg = t & 15;
      const float* src = X + (((size_t)(rows + r)) << 7) + seg * 8;
      *(short8*)(sA + r * LDA + seg * 8) = pack8(*(const float4*)src, *(const float4*)(src + 4));
    }
  } else {
    const unsigned short* X = (const unsigned short*)Xv;
    for (int t = tid; t < 1024; t += 256) {
      const int r = t >> 4, seg = t & 15;
      *(short8*)(sA + r * LDA + seg * 8) =
          *(const short8*)(X + (((size_t)(rows + r)) << 7) + seg * 8);
    }
  }
  __syncthreads();

  const int half = w >> 1;            // 0: center (Wa), 1: nbr (Wb)
  const int cb = (w & 1) * 64;
  f32x4 acc[4][4];
#pragma unroll
  for (int m = 0; m < 4; ++m)
#pragma unroll
    for (int n = 0; n < 4; ++n) acc[m][n] = (f32x4){0, 0, 0, 0};
  gemm64<384, 4>(sA, Wbase + half * 128, lane, cb, acc);

  unsigned short* Y = half ? Yn : Yc;
  const int stride = SPLIT ? 128 : 256;
  const int coff = SPLIT ? 0 : half * 128;
#pragma unroll
  for (int n = 0; n < 4; ++n) {
    const int col = coff + cb + n * 16 + rl;
#pragma unroll
    for (int m = 0; m < 4; ++m)
#pragma unroll
      for (int i = 0; i < 4; ++i)
        Y[(size_t)(rows + m * 16 + h4 + i) * stride + col] = f2bf(acc[m][n][i]);
  }
}

// ---- k1: per-edge MLP (hE part) + masked k-sum + LN1 -> hV1b; stash hE bf16 into outE ----
__global__ __launch_bounds__(256, 4) void k1(
    const float* __restrict__ hV, const float* __restrict__ hE,
    const int* __restrict__ Eidx, const float* __restrict__ mattend,
    const unsigned short* __restrict__ wc, const unsigned short* __restrict__ Y1,
    const float* __restrict__ W1b, const float* __restrict__ W2b,
    const float* __restrict__ W3b, const float* __restrict__ n1g,
    const float* __restrict__ n1b, unsigned short* __restrict__ hV1b,
    float* __restrict__ outE) {
  __shared__ __align__(16) unsigned short sA[64 * LDA];
  __shared__ __align__(16) unsigned short sYc[2 * 128];
  __shared__ float sMask[64];
  __shared__ float sRed[2][128];

  const int tid = threadIdx.x;
  const int lane = tid & 63;
  const int w = tid >> 6;
  const int rl = lane & 15;
  const int h4 = (lane >> 4) << 2;
  const int bid = (blockIdx.x & 7) * 1024 + (blockIdx.x >> 3);  // 1 batch per XCD
  const int v0 = bid << 1;
  const int b = v0 >> 11;
  const int n0 = v0 & (N_ - 1);
  const int bBase = b * N_;

  const unsigned short* W1c = wc;          // [128][384]
  const unsigned short* W2c = wc + 49152;  // [128][128]
  const unsigned short* W3c = wc + 65536;  // [128][128]

  // stage hE rows (fp32->bf16) into sA + stash bf16 copy into outE rows' 2nd half
  for (int t = tid; t < 1024; t += 256) {
    const int r = t >> 4, seg = t & 15;
    const int g = r >> 5, kk = r & 31;
    const int kc = kk < K_ ? kk : K_ - 1;
    const size_t e = (size_t)(bBase + n0 + g) * K_ + kc;
    const float* src = hE + (e << 7) + seg * 8;
    const short8 o = pack8(*(const float4*)src, *(const float4*)(src + 4));
    *(short8*)(sA + r * LDA + seg * 8) = o;
    if (kk < K_)
      *(short8*)((unsigned short*)(outE + (e << 7)) + 128 + seg * 8) = o;
  }
  {
    const int g = tid >> 7, c = tid & 127;
    sYc[g * 128 + c] = Y1[(size_t)(bBase + n0 + g) * 256 + c];
  }
  if (tid < 64) {
    const int g = tid >> 5, kk = tid & 31;
    sMask[tid] = (kk < K_) ? mattend[(bBase + n0 + g) * K_ + kk] : 0.f;
  }
  __syncthreads();

  f32x4 acc[4][2];
  ZERO42(acc)
  gemmT<384>(sA, W1c + 256, lane, w * 32, acc);
  __syncthreads();  // all lanes done reading hE tile

  // stage gathered Yn rows into sA (overwrite hE)
  for (int t = tid; t < 1024; t += 256) {
    const int r = t >> 4, seg = t & 15;
    const int g = r >> 5;
    int kk = r & 31; if (kk >= K_) kk = K_ - 1;
    const int j = Eidx[(bBase + n0 + g) * K_ + kk];
    *(short8*)(sA + r * LDA + seg * 8) =
        *(const short8*)(Y1 + (size_t)(bBase + j) * 256 + 128 + seg * 8);
  }
  __syncthreads();

  // combine: + b1 + Yc + Yn, gelu -> X1 in place (lane-private cells)
  {
    float4 b1v[2];
    b1v[0] = *(const float4*)(W1b + w * 32 + h4);
    b1v[1] = *(const float4*)(W1b + w * 32 + 16 + h4);
#pragma unroll
    for (int et = 0; et < 4; ++et) {
      const int e = et * 16 + rl;
      const int g = et >> 1;
#pragma unroll
      for (int fn = 0; fn < 2; ++fn) {
        const int f0 = w * 32 + fn * 16 + h4;
        const ushort4 yc = *(const ushort4*)(sYc + g * 128 + f0);
        const ushort4 yn = *(const ushort4*)(sA + e * LDA + f0);
        const float x0 = gelu_t(acc[et][fn][0] + b1v[fn].x + bf2f(yc.x) + bf2f(yn.x));
        const float x1 = gelu_t(acc[et][fn][1] + b1v[fn].y + bf2f(yc.y) + bf2f(yn.y));
        const float x2 = gelu_t(acc[et][fn][2] + b1v[fn].z + bf2f(yc.z) + bf2f(yn.z));
        const float x3 = gelu_t(acc[et][fn][3] + b1v[fn].w + bf2f(yc.w) + bf2f(yn.w));
        uint2 o; o.x = pkbf(x0, x1); o.y = pkbf(x2, x3);
        *(uint2*)(sA + e * LDA + f0) = o;
      }
    }
  }
  __syncthreads();

  f32x4 acc2[4][2];
  ZERO42(acc2)
  gemmT<128>(sA, W2c, lane, w * 32, acc2);
  __syncthreads();
  {
    float4 b2v[2];
    b2v[0] = *(const float4*)(W2b + w * 32 + h4);
    b2v[1] = *(const float4*)(W2b + w * 32 + 16 + h4);
#pragma unroll
    for (int et = 0; et < 4; ++et) {
      const int e = et * 16 + rl;
#pragma unroll
      for (int fn = 0; fn < 2; ++fn) {
        const int f0 = w * 32 + fn * 16 + h4;
        const float x0 = gelu_t(acc2[et][fn][0] + b2v[fn].x);
        const float x1 = gelu_t(acc2[et][fn][1] + b2v[fn].y);
        const float x2 = gelu_t(acc2[et][fn][2] + b2v[fn].z);
        const float x3 = gelu_t(acc2[et][fn][3] + b2v[fn].w);
        uint2 o; o.x = pkbf(x0, x1); o.y = pkbf(x2, x3);
        *(uint2*)(sA + e * LDA + f0) = o;
      }
    }
  }
  __syncthreads();

  f32x4 acc3[4][2];
  ZERO42(acc3)
  gemmT<128>(sA, W3c, lane, w * 32, acc3);
  __syncthreads();  // all X2 reads done

  // masked messages -> bf16 in place
  {
    float4 b3v[2];
    b3v[0] = *(const float4*)(W3b + w * 32 + h4);
    b3v[1] = *(const float4*)(W3b + w * 32 + 16 + h4);
#pragma unroll
    for (int et = 0; et < 4; ++et) {
      const int e = et * 16 + rl;
      const float mk = sMask[e];
#pragma unroll
      for (int fn = 0; fn < 2; ++fn) {
        const int f0 = w * 32 + fn * 16 + h4;
        uint2 o;
        o.x = pkbf((acc3[et][fn][0] + b3v[fn].x) * mk, (acc3[et][fn][1] + b3v[fn].y) * mk);
        o.y = pkbf((acc3[et][fn][2] + b3v[fn].z) * mk, (acc3[et][fn][3] + b3v[fn].w) * mk);
        *(uint2*)(sA + e * LDA + f0) = o;
      }
    }
  }
  __syncthreads();

  // column sums over k, then LN1
  {
    const int g = tid >> 7, f = tid & 127;
    float s = 0.f;
#pragma unroll
    for (int kk = 0; kk < 32; ++kk) s += bf2f(sA[(g * 32 + kk) * LDA + f]);
    sRed[g][f] = s;
  }
  __syncthreads();

  if (w < 2) {
    const size_t base = ((size_t)(bBase + n0 + w)) << 7;
    const float x0 = hV[base + lane] + sRed[w][lane] * (1.0f / 30.0f);
    const float x1 = hV[base + 64 + lane] + sRed[w][64 + lane] * (1.0f / 30.0f);
    float s = x0 + x1;
#pragma unroll
    for (int o = 1; o < 64; o <<= 1) s += __shfl_xor(s, o);
    const float mean = s * (1.0f / 128.0f);
    const float d0 = x0 - mean, d1 = x1 - mean;
    float vs = d0 * d0 + d1 * d1;
#pragma unroll
    for (int o = 1; o < 64; o <<= 1) vs += __shfl_xor(vs, o);
    const float inv = rsqrtf(vs * (1.0f / 128.0f) + EPS_);
    hV1b[base + lane] = f2bf(n1g[lane] * (d0 * inv) + n1b[lane]);
    hV1b[base + 64 + lane] = f2bf(n1g[64 + lane] * (d1 * inv) + n1b[64 + lane]);
  }
}

// ---- k2: FFN + LN2 + mask_V -> outV (fp32) and hV2c (bf16); 16 rows/block ----
__global__ __launch_bounds__(256) void k2(
    const unsigned short* __restrict__ hV1b, const unsigned short* __restrict__ wc,
    const float* __restrict__ dinb, const float* __restrict__ doutb,
    const float* __restrict__ n2g, const float* __restrict__ n2b,
    const float* __restrict__ maskV, float* __restrict__ outV,
    unsigned short* __restrict__ hV2c) {
  __shared__ __align__(16) unsigned short sT[16 * LDA];
  __shared__ float sStat[16][2][4];

  const int tid = threadIdx.x;
  const int lane = tid & 63;
  const int w = tid >> 6;
  const int rl = lane & 15;
  const int h4 = (lane >> 4) << 2;
  const int klo = (lane >> 4) << 3;
  const int rowbase = blockIdx.x << 4;

  const unsigned short* dinc = wc + 163840;   // [512][128]
  const unsigned short* doutc = wc + 229376;  // [128][512]

  short8 ef[4];
#pragma unroll
  for (int ks = 0; ks < 4; ++ks)
    ef[ks] = *(const short8*)(hV1b + (((size_t)(rowbase + rl)) << 7) + ks * 32 + klo);

  f32x4 acc2[2];
  acc2[0] = (f32x4){0, 0, 0, 0}; acc2[1] = (f32x4){0, 0, 0, 0};

  for (int c = 0; c < 4; ++c) {
    f32x4 acc1[2];
    acc1[0] = (f32x4){0, 0, 0, 0}; acc1[1] = (f32x4){0, 0, 0, 0};
#pragma unroll
    for (int ks = 0; ks < 4; ++ks)
#pragma unroll
      for (int fn = 0; fn < 2; ++fn) {
        const short8 wf = *(const short8*)(dinc + (size_t)(c * 128 + w * 32 + fn * 16 + rl) * 128 + ks * 32 + klo);
        acc1[fn] = __builtin_amdgcn_mfma_f32_16x16x32_bf16(wf, ef[ks], acc1[fn], 0, 0, 0);
      }
    __syncthreads();  // previous chunk's GEMM2 reads of sT done
    {
      float4 db[2];
      db[0] = *(const float4*)(dinb + c * 128 + w * 32 + h4);
      db[1] = *(const float4*)(dinb + c * 128 + w * 32 + 16 + h4);
#pragma unroll
      for (int fn = 0; fn < 2; ++fn) {
        const int f0 = w * 32 + fn * 16 + h4;
        const float x0 = gelu_t(acc1[fn][0] + db[fn].x);
        const float x1 = gelu_t(acc1[fn][1] + db[fn].y);
        const float x2 = gelu_t(acc1[fn][2] + db[fn].z);
        const float x3 = gelu_t(acc1[fn][3] + db[fn].w);
        uint2 o; o.x = pkbf(x0, x1); o.y = pkbf(x2, x3);
        *(uint2*)(sT + rl * LDA + f0) = o;
      }
    }
    __syncthreads();
#pragma unroll
    for (int ks = 0; ks < 4; ++ks) {
      const short8 xf = *(const short8*)(sT + rl * LDA + ks * 32 + klo);
#pragma unroll
      for (int fn = 0; fn < 2; ++fn) {
        const short8 wf2 = *(const short8*)(doutc + (size_t)(w * 32 + fn * 16 + rl) * 512 + c * 128 + ks * 32 + klo);
        acc2[fn] = __builtin_amdgcn_mfma_f32_16x16x32_bf16(wf2, xf, acc2[fn], 0, 0, 0);
      }
    }
  }

  const int row = rl;
  const int grow = rowbase + row;
  {
    float4 wbv[2];
    wbv[0] = *(const float4*)(doutb + w * 32 + h4);
    wbv[1] = *(const float4*)(doutb + w * 32 + 16 + h4);
    float s = 0.f, ss = 0.f;
#pragma unroll
    for (int fn = 0; fn < 2; ++fn) {
      const int f0 = w * 32 + fn * 16 + h4;
      const ushort4 rr = *(const ushort4*)(hV1b + (((size_t)grow) << 7) + f0);
      const float x0 = acc2[fn][0] + wbv[fn].x + bf2f(rr.x);
      const float x1 = acc2[fn][1] + wbv[fn].y + bf2f(rr.y);
      const float x2 = acc2[fn][2] + wbv[fn].z + bf2f(rr.z);
      const float x3 = acc2[fn][3] + wbv[fn].w + bf2f(rr.w);
      acc2[fn] = (f32x4){x0, x1, x2, x3};
      s += x0 + x1 + x2 + x3;
      ss += x0 * x0 + x1 * x1 + x2 * x2 + x3 * x3;
    }
    s += __shfl_xor(s, 16); s += __shfl_xor(s, 32);
    ss += __shfl_xor(ss, 16); ss += __shfl_xor(ss, 32);
    if (lane < 16) { sStat[row][0][w] = s; sStat[row][1][w] = ss; }
  }
  __syncthreads();
  {
    const float sum = sStat[row][0][0] + sStat[row][0][1] + sStat[row][0][2] + sStat[row][0][3];
    const float ssq = sStat[row][1][0] + sStat[row][1][1] + sStat[row][1][2] + sStat[row][1][3];
    const float mean = sum * (1.0f / 128.0f);
    const float inv = rsqrtf(ssq * (1.0f / 128.0f) - mean * mean + EPS_);
    const float mv = maskV[grow];
#pragma unroll
    for (int fn = 0; fn < 2; ++fn) {
      const int f0 = w * 32 + fn * 16 + h4;
      const float4 gv = *(const float4*)(n2g + f0);
      const float4 bv = *(const float4*)(n2b + f0);
      const float y0 = (gv.x * (acc2[fn][0] - mean) * inv + bv.x) * mv;
      const float y1 = (gv.y * (acc2[fn][1] - mean) * inv + bv.y) * mv;
      const float y2 = (gv.z * (acc2[fn][2] - mean) * inv + bv.z) * mv;
      const float y3 = (gv.w * (acc2[fn][3] - mean) * inv + bv.w) * mv;
      *(float4*)(outV + (((size_t)grow) << 7) + f0) = make_float4(y0, y1, y2, y3);
      uint2 o; o.x = pkbf(y0, y1); o.y = pkbf(y2, y3);
      *(uint2*)(hV2c + (((size_t)grow) << 7) + f0) = o;
    }
  }
}

// ---- k3: edge MLP + residual(stash bf16) + LN3 -> outE (single LDS buffer) ----
__global__ __launch_bounds__(256, 4) void k3(
    const int* __restrict__ Eidx, const unsigned short* __restrict__ wc,
    const unsigned short* __restrict__ Y2c, const unsigned short* __restrict__ Y2n,
    const float* __restrict__ W11b, const float* __restrict__ W12b,
    const float* __restrict__ W13b, const float* __restrict__ n3g,
    const float* __restrict__ n3b, float* __restrict__ outE) {
  __shared__ __align__(16) unsigned short sA[64 * LDA];
  __shared__ unsigned short sYc[2 * 128];
  __shared__ float sStat[64][2][4];

  const int tid = threadIdx.x;
  const int lane = tid & 63;
  const int w = tid >> 6;
  const int rl = lane & 15;
  const int h4 = (lane >> 4) << 2;
  const int bid = (blockIdx.x & 7) * 1024 + (blockIdx.x >> 3);
  const int v0 = bid << 1;
  const int b = v0 >> 11;
  const int n0 = v0 & (N_ - 1);
  const int bBase = b * N_;

  const unsigned short* W11c = wc + 81920;
  const unsigned short* W12c = wc + 131072;
  const unsigned short* W13c = wc + 147456;

  // stage hE bf16 rows from outE second halves (stash written by k1)
  for (int t = tid; t < 1024; t += 256) {
    const int r = t >> 4, seg = t & 15;
    const int g = r >> 5;
    int kk = r & 31; if (kk >= K_) kk = K_ - 1;
    const size_t e = (size_t)(bBase + n0 + g) * K_ + kk;
    *(short8*)(sA + r * LDA + seg * 8) =
        *(const short8*)((const unsigned short*)(outE + (e << 7)) + 128 + seg * 8);
  }
  {
    const int g = tid >> 7, c = tid & 127;
    sYc[g * 128 + c] = Y2c[(size_t)(bBase + n0 + g) * 128 + c];
  }
  __syncthreads();

  f32x4 acc[4][2];
  ZERO42(acc)
  gemm64<384, 2>(sA, W11c + 256, lane, w * 32, acc);
  __syncthreads();  // all lanes done reading hE tile

  // stage gathered Y2n rows into sA (overwrite hE)
  for (int t = tid; t < 1024; t += 256) {
    const int r = t >> 4, seg = t & 15;
    const int g = r >> 5;
    int kk = r & 31; if (kk >= K_) kk = K_ - 1;
    const int j = Eidx[(bBase + n0 + g) * K_ + kk];
    *(short8*)(sA + r * LDA + seg * 8) =
        *(const short8*)(Y2n + (size_t)(bBase + j) * 128 + seg * 8);
  }
  __syncthreads();

  // combine: x = acc + b + Yc + Yn(same cell), gelu -> X1 in place
#pragma unroll
  for (int n = 0; n < 2; ++n) {
    const int f = w * 32 + n * 16 + rl;
    const float bb = W11b[f];
#pragma unroll
    for (int m = 0; m < 4; ++m)
#pragma unroll
      for (int i = 0; i < 4; ++i) {
        const int e = m * 16 + h4 + i;
        const float x = acc[m][n][i] + bb + bf2f(sYc[(e >> 5) * 128 + f]) + bf2f(sA[e * LDA + f]);
        sA[e * LDA + f] = f2bf(gelu_t(x));
      }
  }
  __syncthreads();

  f32x4 acc2[4][2];
  ZERO42(acc2)
  gemm64<128, 2>(sA, W12c, lane, w * 32, acc2);
  __syncthreads();
#pragma unroll
  for (int n = 0; n < 2; ++n) {
    const int f = w * 32 + n * 16 + rl;
    const float bb = W12b[f];
#pragma unroll
    for (int m = 0; m < 4; ++m)
#pragma unroll
      for (int i = 0; i < 4; ++i) {
        const int e = m * 16 + h4 + i;
        sA[e * LDA + f] = f2bf(gelu_t(acc2[m][n][i] + bb));
      }
  }
  __syncthreads();

  f32x4 acc3[4][2];
  ZERO42(acc3)
  gemm64<128, 2>(sA, W13c, lane, w * 32, acc3);

  // epilogue: x = msg + b + hE (bf16 stash from global, L2-hot); LN3 with 4-wave partials
  float gc[2], bc[2], wb[2];
#pragma unroll
  for (int n = 0; n < 2; ++n) {
    const int f = w * 32 + n * 16 + rl;
    gc[n] = n3g[f]; bc[n] = n3b[f]; wb[n] = W13b[f];
  }
#pragma unroll
  for (int m = 0; m < 4; ++m)
#pragma unroll
    for (int i = 0; i < 4; ++i) {
      const int e = m * 16 + h4 + i;
      const int g = e >> 5, kk = e & 31;
      const bool valid = kk < K_;
      const size_t erow = (size_t)((bBase + n0 + g) * K_ + (valid ? kk : K_ - 1));
      const unsigned short* er =
          (const unsigned short*)(outE + (erow << 7)) + 128 + w * 32 + rl;
      float s = 0.f, ss = 0.f;
#pragma unroll
      for (int n = 0; n < 2; ++n) {
        float x = acc3[m][n][i] + wb[n];
        if (valid) x += bf2f(er[n * 16]);
        acc3[m][n][i] = x;
        s += x; ss += x * x;
      }
#pragma unroll
      for (int o = 1; o <= 8; o <<= 1) { s += __shfl_xor(s, o); ss += __shfl_xor(ss, o); }
      if (rl == 0) { sStat[e][0][w] = s; sStat[e][1][w] = ss; }
    }
  __syncthreads();
#pragma unroll
  for (int m = 0; m < 4; ++m)
#pragma unroll
    for (int i = 0; i < 4; ++i) {
      const int e = m * 16 + h4 + i;
      const int g = e >> 5, kk = e & 31;
      if (kk >= K_) continue;
      const float sum = sStat[e][0][0] + sStat[e][0][1] + sStat[e][0][2] + sStat[e][0][3];
      const float ssq = sStat[e][1][0] + sStat[e][1][1] + sStat[e][1][2] + sStat[e][1][3];
      const float mean = sum * (1.0f / 128.0f);
      const float inv = rsqrtf(ssq * (1.0f / 128.0f) - mean * mean + EPS_);
      float* dst = outE + (((size_t)((bBase + n0 + g) * K_ + kk)) << 7) + w * 32 + rl;
#pragma unroll
      for (int n = 0; n < 2; ++n)
        dst[n * 16] = gc[n] * (acc3[m][n][i] - mean) * inv + bc[n];
    }
}

extern "C" void kernel_launch(void* const* d_in, const int* in_sizes, int n_in,
                              void* d_out, int out_size, void* d_ws, size_t ws_size,
                              hipStream_t stream) {
  const float* hV = (const float*)d_in[0];
  const float* hE = (const float*)d_in[1];
  const int* Eidx = (const int*)d_in[2];
  const float* maskV = (const float*)d_in[3];
  const float* mattend = (const float*)d_in[4];
  const float* W1w = (const float*)d_in[5];   const float* W1b = (const float*)d_in[6];
  const float* W2w = (const float*)d_in[7];   const float* W2b = (const float*)d_in[8];
  const float* W3w = (const float*)d_in[9];   const float* W3b = (const float*)d_in[10];
  const float* W11w = (const float*)d_in[11]; const float* W11b = (const float*)d_in[12];
  const float* W12w = (const float*)d_in[13]; const float* W12b = (const float*)d_in[14];
  const float* W13w = (const float*)d_in[15]; const float* W13b = (const float*)d_in[16];
  const float* n1g = (const float*)d_in[17];  const float* n1b = (const float*)d_in[18];
  const float* n2g = (const float*)d_in[19];  const float* n2b = (const float*)d_in[20];
  const float* n3g = (const float*)d_in[21];  const float* n3b = (const float*)d_in[22];
  const float* dinw = (const float*)d_in[23]; const float* dinb = (const float*)d_in[24];
  const float* doutw = (const float*)d_in[25]; const float* doutb = (const float*)d_in[26];

  // ws layout (bytes), peak == proven 13,172,736:
  //   [0, 589824)          wc  (bf16 weights)
  //   [589824, 8978432)    Region1: Y1 (k1 phase) -> hV2c (1st half) + Y2c (2nd half)
  //   [8978432, 13172736)  Region2: hV1b (k1/k2) -> Y2n (k3 phase)
  unsigned short* wc   = (unsigned short*)d_ws;
  unsigned short* R1   = wc + 294912;
  unsigned short* R2   = R1 + 4194304;
  unsigned short* Y1   = R1;            // [BN][256] bf16
  unsigned short* hV1b = R2;            // [BN][128] bf16
  unsigned short* hV2c = R1;            // [BN][128] bf16 (Y1 dead after k1)
  unsigned short* Y2c  = R1 + 2097152;  // [BN][128] bf16
  unsigned short* Y2n  = R2;            // [BN][128] bf16 (hV1b dead after k2)

  float* outV = (float*)d_out;
  float* outE = outV + (size_t)B_ * N_ * H_;

  prep<<<1152, 256, 0, stream>>>(W1w, W2w, W3w, W11w, W12w, W13w, dinw, doutw, wc);
  preY<true, false><<<256, 256, 0, stream>>>(hV, wc, Y1, Y1);
  k1<<<8192, 256, 0, stream>>>(hV, hE, Eidx, mattend, wc, Y1,
                               W1b, W2b, W3b, n1g, n1b, hV1b, outE);
  k2<<<1024, 256, 0, stream>>>(hV1b, wc, dinb, doutb, n2g, n2b, maskV, outV, hV2c);
  preY<false, true><<<256, 256, 0, stream>>>(hV2c, wc + 81920, Y2c, Y2n);
  k3<<<8192, 256, 0, stream>>>(Eidx, wc, Y2c, Y2n,
                               W11b, W12b, W13b, n3g, n3b, outE);
}

// Round 11
// 452.092 us; speedup vs baseline: 1.0886x; 1.0886x over previous
//
#include <hip/hip_runtime.h>

#define B_ 8
#define N_ 2048
#define K_ 30
#define H_ 128
#define LDA 136
#define LDM 132
#define EPS_ 1e-5f

typedef __attribute__((ext_vector_type(8))) short short8;
typedef __attribute__((ext_vector_type(4))) float f32x4;

// pack 2 f32 -> 2 bf16 (RNE) in one instr
__device__ inline unsigned pkbf(float lo, float hi) {
  unsigned r;
  asm("v_cvt_pk_bf16_f32 %0, %1, %2" : "=v"(r) : "v"(lo), "v"(hi));
  return r;
}

__device__ inline unsigned short f2bf(float f) { return (unsigned short)pkbf(f, f); }

__device__ inline float bf2f(unsigned short h) {
  union { unsigned u; float f; } v; v.u = ((unsigned)h) << 16; return v.f;
}

// tanh-form GELU with fast rcp
__device__ inline float gelu_t(float x) {
  const float p = x * x;
  const float z = x * (1.5957691216057308f + 0.07135481627f * p);
  const float e = exp2f(z * -1.4426950408889634f);  // e^{-z}
  return x * __builtin_amdgcn_rcpf(1.0f + e);
}

__device__ inline short8 pack8(float4 a, float4 b) {
  union { unsigned u[4]; short8 s; } v;
  v.u[0] = pkbf(a.x, a.y); v.u[1] = pkbf(a.z, a.w);
  v.u[2] = pkbf(b.x, b.y); v.u[3] = pkbf(b.z, b.w);
  return v.s;
}

// ---- swapped-operand GEMM: D[feature][edge] (used by k1) ----
template<int LDW>
__device__ inline void gemmT(const unsigned short* __restrict__ sA,
                             const unsigned short* __restrict__ W,
                             int lane, int cb, f32x4 (&acc)[4][2]) {
  const int rl = lane & 15;
  const int klo = (lane >> 4) << 3;
#pragma unroll
  for (int ks = 0; ks < 4; ++ks) {
    short8 wf[2];
#pragma unroll
    for (int fn = 0; fn < 2; ++fn)
      wf[fn] = *(const short8*)(W + (size_t)(cb + fn * 16 + rl) * LDW + ks * 32 + klo);
#pragma unroll
    for (int et = 0; et < 4; ++et) {
      const short8 ef = *(const short8*)(sA + (et * 16 + rl) * LDA + ks * 32 + klo);
      acc[et][0] = __builtin_amdgcn_mfma_f32_16x16x32_bf16(wf[0], ef, acc[et][0], 0, 0, 0);
      acc[et][1] = __builtin_amdgcn_mfma_f32_16x16x32_bf16(wf[1], ef, acc[et][1], 0, 0, 0);
    }
  }
}

#define ZERO42(A) \
  _Pragma("unroll") for (int e_ = 0; e_ < 4; ++e_) { A[e_][0] = (f32x4){0,0,0,0}; A[e_][1] = (f32x4){0,0,0,0}; }

// ---- old-layout 64-row wave GEMM (preY + k3): D[row][feature] ----
template<int LDW, int NN>
__device__ inline void gemm64(const unsigned short* __restrict__ sA,
                              const unsigned short* __restrict__ W,
                              int lane, int cb, f32x4 (&acc)[4][NN]) {
  const int rl = lane & 15;
  const int klo = (lane >> 4) << 3;
#pragma unroll
  for (int ks = 0; ks < 4; ++ks) {
    short8 a[4];
#pragma unroll
    for (int m = 0; m < 4; ++m)
      a[m] = *(const short8*)(sA + (m * 16 + rl) * LDA + ks * 32 + klo);
#pragma unroll
    for (int n = 0; n < NN; ++n) {
      const short8 b8 = *(const short8*)(W + (size_t)(cb + n * 16 + rl) * LDW + ks * 32 + klo);
#pragma unroll
      for (int m = 0; m < 4; ++m)
        acc[m][n] = __builtin_amdgcn_mfma_f32_16x16x32_bf16(a[m], b8, acc[m][n], 0, 0, 0);
    }
  }
}

// ---- prep: weights fp32 -> bf16 ----
__global__ __launch_bounds__(256) void prep(const float* __restrict__ w1, const float* __restrict__ w2,
                                            const float* __restrict__ w3, const float* __restrict__ w11,
                                            const float* __restrict__ w12, const float* __restrict__ w13,
                                            const float* __restrict__ din, const float* __restrict__ dout,
                                            unsigned short* __restrict__ dst) {
  const int i = blockIdx.x * 256 + threadIdx.x;  // grid covers exactly 294912
  const float* s; int off;
  if (i < 49152)       { s = w1;  off = 0; }
  else if (i < 65536)  { s = w2;  off = 49152; }
  else if (i < 81920)  { s = w3;  off = 65536; }
  else if (i < 131072) { s = w11; off = 81920; }
  else if (i < 147456) { s = w12; off = 131072; }
  else if (i < 163840) { s = w13; off = 147456; }
  else if (i < 229376) { s = din; off = 163840; }
  else                 { s = dout; off = 229376; }
  dst[i] = f2bf(s[i - off]);
}

// ---- pre-GEMM: Y = X @ [Wa|Wb]^T -> 256 cols (center|nbr halves) ----
template<bool F32SRC, bool SPLIT>
__global__ __launch_bounds__(256) void preY(const void* __restrict__ Xv,
                                            const unsigned short* __restrict__ Wbase,
                                            unsigned short* __restrict__ Yc,
                                            unsigned short* __restrict__ Yn) {
  __shared__ __align__(16) unsigned short sA[64 * LDA];
  const int tid = threadIdx.x;
  const int lane = tid & 63;
  const int w = tid >> 6;
  const int rows = blockIdx.x << 6;
  const int rl = lane & 15;
  const int h4 = (lane >> 4) << 2;

  if (F32SRC) {
    const float* X = (const float*)Xv;
    for (int t = tid; t < 1024; t += 256) {
      const int r = t >> 4, seg = t & 15;
      const float* src = X + (((size_t)(rows + r)) << 7) + seg * 8;
      *(short8*)(sA + r * LDA + seg * 8) = pack8(*(const float4*)src, *(const float4*)(src + 4));
    }
  } else {
    const unsigned short* X = (const unsigned short*)Xv;
    for (int t = tid; t < 1024; t += 256) {
      const int r = t >> 4, seg = t & 15;
      *(short8*)(sA + r * LDA + seg * 8) =
          *(const short8*)(X + (((size_t)(rows + r)) << 7) + seg * 8);
    }
  }
  __syncthreads();

  const int half = w >> 1;            // 0: center (Wa), 1: nbr (Wb)
  const int cb = (w & 1) * 64;
  f32x4 acc[4][4];
#pragma unroll
  for (int m = 0; m < 4; ++m)
#pragma unroll
    for (int n = 0; n < 4; ++n) acc[m][n] = (f32x4){0, 0, 0, 0};
  gemm64<384, 4>(sA, Wbase + half * 128, lane, cb, acc);

  unsigned short* Y = half ? Yn : Yc;
  const int stride = SPLIT ? 128 : 256;
  const int coff = SPLIT ? 0 : half * 128;
#pragma unroll
  for (int n = 0; n < 4; ++n) {
    const int col = coff + cb + n * 16 + rl;
#pragma unroll
    for (int m = 0; m < 4; ++m)
#pragma unroll
      for (int i = 0; i < 4; ++i)
        Y[(size_t)(rows + m * 16 + h4 + i) * stride + col] = f2bf(acc[m][n][i]);
  }
}

// ---- k1: per-edge MLP (hE part) + masked k-sum + LN1 -> hV1b; side-writes hEb stash ----
__global__ __launch_bounds__(256, 4) void k1(
    const float* __restrict__ hV, const float* __restrict__ hE,
    const int* __restrict__ Eidx, const float* __restrict__ mattend,
    const unsigned short* __restrict__ wc, const unsigned short* __restrict__ Y1,
    const float* __restrict__ W1b, const float* __restrict__ W2b,
    const float* __restrict__ W3b, const float* __restrict__ n1g,
    const float* __restrict__ n1b, unsigned short* __restrict__ hV1b,
    float* __restrict__ outE) {
  __shared__ __align__(16) unsigned short sBuf[2 * 64 * LDA];
  __shared__ __align__(16) unsigned short sYc[2 * 128];
  __shared__ float sMask[64];
  __shared__ float sRed[2][128];
  unsigned short* sE = sBuf;
  unsigned short* sG = sBuf + 64 * LDA;
  float* sM = (float*)sBuf;  // 64*LDM fp32 after GEMM3

  const int tid = threadIdx.x;
  const int lane = tid & 63;
  const int w = tid >> 6;
  const int rl = lane & 15;
  const int h4 = (lane >> 4) << 2;
  const int bid = (blockIdx.x & 7) * 1024 + (blockIdx.x >> 3);  // 1 batch per XCD
  const int v0 = bid << 1;
  const int b = v0 >> 11;
  const int n0 = v0 & (N_ - 1);
  const int bBase = b * N_;

  const unsigned short* W1c = wc;          // [128][384]
  const unsigned short* W2c = wc + 49152;  // [128][128]
  const unsigned short* W3c = wc + 65536;  // [128][128]

  // stage hE rows (fp32->bf16) + side-write bf16 stash into outE rows' 2nd half
  for (int t = tid; t < 1024; t += 256) {
    const int r = t >> 4, seg = t & 15;
    const int g = r >> 5, kk = r & 31;
    const int kc = kk < K_ ? kk : K_ - 1;
    const size_t e = (size_t)(bBase + n0 + g) * K_ + kc;
    const float* src = hE + (e << 7) + seg * 8;
    const short8 o = pack8(*(const float4*)src, *(const float4*)(src + 4));
    *(short8*)(sE + r * LDA + seg * 8) = o;
    if (kk < K_)
      *(short8*)((unsigned short*)(outE + (e << 7)) + 128 + seg * 8) = o;
  }
  // stage gathered Yn rows
  for (int t = tid; t < 1024; t += 256) {
    const int r = t >> 4, seg = t & 15;
    const int g = r >> 5;
    int kk = r & 31; if (kk >= K_) kk = K_ - 1;
    const int j = Eidx[(bBase + n0 + g) * K_ + kk];
    *(short8*)(sG + r * LDA + seg * 8) =
        *(const short8*)(Y1 + (size_t)(bBase + j) * 256 + 128 + seg * 8);
  }
  {
    const int g = tid >> 7, c = tid & 127;
    sYc[g * 128 + c] = Y1[(size_t)(bBase + n0 + g) * 256 + c];
  }
  if (tid < 64) {
    const int g = tid >> 5, kk = tid & 31;
    sMask[tid] = (kk < K_) ? mattend[(bBase + n0 + g) * K_ + kk] : 0.f;
  }
  __syncthreads();

  f32x4 acc[4][2];
  ZERO42(acc)
  gemmT<384>(sE, W1c + 256, lane, w * 32, acc);

  // combine: + b1 + Yc + Yn, gelu -> X1 into sG (lane-private 4-feature cells)
  {
    float4 b1v[2];
    b1v[0] = *(const float4*)(W1b + w * 32 + h4);
    b1v[1] = *(const float4*)(W1b + w * 32 + 16 + h4);
#pragma unroll
    for (int et = 0; et < 4; ++et) {
      const int e = et * 16 + rl;
      const int g = et >> 1;
#pragma unroll
      for (int fn = 0; fn < 2; ++fn) {
        const int f0 = w * 32 + fn * 16 + h4;
        const ushort4 yc = *(const ushort4*)(sYc + g * 128 + f0);
        const ushort4 yn = *(const ushort4*)(sG + e * LDA + f0);
        const float x0 = gelu_t(acc[et][fn][0] + b1v[fn].x + bf2f(yc.x) + bf2f(yn.x));
        const float x1 = gelu_t(acc[et][fn][1] + b1v[fn].y + bf2f(yc.y) + bf2f(yn.y));
        const float x2 = gelu_t(acc[et][fn][2] + b1v[fn].z + bf2f(yc.z) + bf2f(yn.z));
        const float x3 = gelu_t(acc[et][fn][3] + b1v[fn].w + bf2f(yc.w) + bf2f(yn.w));
        uint2 o; o.x = pkbf(x0, x1); o.y = pkbf(x2, x3);
        *(uint2*)(sG + e * LDA + f0) = o;
      }
    }
  }
  __syncthreads();

  f32x4 acc2[4][2];
  ZERO42(acc2)
  gemmT<128>(sG, W2c, lane, w * 32, acc2);
  __syncthreads();
  {
    float4 b2v[2];
    b2v[0] = *(const float4*)(W2b + w * 32 + h4);
    b2v[1] = *(const float4*)(W2b + w * 32 + 16 + h4);
#pragma unroll
    for (int et = 0; et < 4; ++et) {
      const int e = et * 16 + rl;
#pragma unroll
      for (int fn = 0; fn < 2; ++fn) {
        const int f0 = w * 32 + fn * 16 + h4;
        const float x0 = gelu_t(acc2[et][fn][0] + b2v[fn].x);
        const float x1 = gelu_t(acc2[et][fn][1] + b2v[fn].y);
        const float x2 = gelu_t(acc2[et][fn][2] + b2v[fn].z);
        const float x3 = gelu_t(acc2[et][fn][3] + b2v[fn].w);
        uint2 o; o.x = pkbf(x0, x1); o.y = pkbf(x2, x3);
        *(uint2*)(sG + e * LDA + f0) = o;
      }
    }
  }
  __syncthreads();

  f32x4 acc3[4][2];
  ZERO42(acc3)
  gemmT<128>(sG, W3c, lane, w * 32, acc3);
  __syncthreads();  // all LDS reads done; sBuf becomes sM (fp32 masked msgs)

  {
    float4 b3v[2];
    b3v[0] = *(const float4*)(W3b + w * 32 + h4);
    b3v[1] = *(const float4*)(W3b + w * 32 + 16 + h4);
#pragma unroll
    for (int et = 0; et < 4; ++et) {
      const int e = et * 16 + rl;
      const float mk = sMask[e];
#pragma unroll
      for (int fn = 0; fn < 2; ++fn) {
        const int f0 = w * 32 + fn * 16 + h4;
        const float4 v = make_float4((acc3[et][fn][0] + b3v[fn].x) * mk,
                                     (acc3[et][fn][1] + b3v[fn].y) * mk,
                                     (acc3[et][fn][2] + b3v[fn].z) * mk,
                                     (acc3[et][fn][3] + b3v[fn].w) * mk);
        *(float4*)(sM + e * LDM + f0) = v;
      }
    }
  }
  __syncthreads();

  // column sums over k (fp32), then LN1
  {
    const int g = tid >> 7, f = tid & 127;
    float s = 0.f;
#pragma unroll
    for (int kk = 0; kk < 32; ++kk) s += sM[(g * 32 + kk) * LDM + f];
    sRed[g][f] = s;
  }
  __syncthreads();

  if (w < 2) {
    const size_t base = ((size_t)(bBase + n0 + w)) << 7;
    const float x0 = hV[base + lane] + sRed[w][lane] * (1.0f / 30.0f);
    const float x1 = hV[base + 64 + lane] + sRed[w][64 + lane] * (1.0f / 30.0f);
    float s = x0 + x1;
#pragma unroll
    for (int o = 1; o < 64; o <<= 1) s += __shfl_xor(s, o);
    const float mean = s * (1.0f / 128.0f);
    const float d0 = x0 - mean, d1 = x1 - mean;
    float vs = d0 * d0 + d1 * d1;
#pragma unroll
    for (int o = 1; o < 64; o <<= 1) vs += __shfl_xor(vs, o);
    const float inv = rsqrtf(vs * (1.0f / 128.0f) + EPS_);
    hV1b[base + lane] = f2bf(n1g[lane] * (d0 * inv) + n1b[lane]);
    hV1b[base + 64 + lane] = f2bf(n1g[64 + lane] * (d1 * inv) + n1b[64 + lane]);
  }
}

// ---- k2: FFN + LN2 + mask_V -> outV (fp32) and hV2c (bf16); 16 rows/block ----
__global__ __launch_bounds__(256) void k2(
    const unsigned short* __restrict__ hV1b, const unsigned short* __restrict__ wc,
    const float* __restrict__ dinb, const float* __restrict__ doutb,
    const float* __restrict__ n2g, const float* __restrict__ n2b,
    const float* __restrict__ maskV, float* __restrict__ outV,
    unsigned short* __restrict__ hV2c) {
  __shared__ __align__(16) unsigned short sT[16 * LDA];
  __shared__ float sStat[16][2][4];

  const int tid = threadIdx.x;
  const int lane = tid & 63;
  const int w = tid >> 6;
  const int rl = lane & 15;
  const int h4 = (lane >> 4) << 2;
  const int klo = (lane >> 4) << 3;
  const int rowbase = blockIdx.x << 4;

  const unsigned short* dinc = wc + 163840;   // [512][128]
  const unsigned short* doutc = wc + 229376;  // [128][512]

  short8 ef[4];
#pragma unroll
  for (int ks = 0; ks < 4; ++ks)
    ef[ks] = *(const short8*)(hV1b + (((size_t)(rowbase + rl)) << 7) + ks * 32 + klo);

  f32x4 acc2[2];
  acc2[0] = (f32x4){0, 0, 0, 0}; acc2[1] = (f32x4){0, 0, 0, 0};

  for (int c = 0; c < 4; ++c) {
    f32x4 acc1[2];
    acc1[0] = (f32x4){0, 0, 0, 0}; acc1[1] = (f32x4){0, 0, 0, 0};
#pragma unroll
    for (int ks = 0; ks < 4; ++ks)
#pragma unroll
      for (int fn = 0; fn < 2; ++fn) {
        const short8 wf = *(const short8*)(dinc + (size_t)(c * 128 + w * 32 + fn * 16 + rl) * 128 + ks * 32 + klo);
        acc1[fn] = __builtin_amdgcn_mfma_f32_16x16x32_bf16(wf, ef[ks], acc1[fn], 0, 0, 0);
      }
    __syncthreads();  // previous chunk's GEMM2 reads of sT done
    {
      float4 db[2];
      db[0] = *(const float4*)(dinb + c * 128 + w * 32 + h4);
      db[1] = *(const float4*)(dinb + c * 128 + w * 32 + 16 + h4);
#pragma unroll
      for (int fn = 0; fn < 2; ++fn) {
        const int f0 = w * 32 + fn * 16 + h4;
        const float x0 = gelu_t(acc1[fn][0] + db[fn].x);
        const float x1 = gelu_t(acc1[fn][1] + db[fn].y);
        const float x2 = gelu_t(acc1[fn][2] + db[fn].z);
        const float x3 = gelu_t(acc1[fn][3] + db[fn].w);
        uint2 o; o.x = pkbf(x0, x1); o.y = pkbf(x2, x3);
        *(uint2*)(sT + rl * LDA + f0) = o;
      }
    }
    __syncthreads();
#pragma unroll
    for (int ks = 0; ks < 4; ++ks) {
      const short8 xf = *(const short8*)(sT + rl * LDA + ks * 32 + klo);
#pragma unroll
      for (int fn = 0; fn < 2; ++fn) {
        const short8 wf2 = *(const short8*)(doutc + (size_t)(w * 32 + fn * 16 + rl) * 512 + c * 128 + ks * 32 + klo);
        acc2[fn] = __builtin_amdgcn_mfma_f32_16x16x32_bf16(wf2, xf, acc2[fn], 0, 0, 0);
      }
    }
  }

  // epilogue: lane owns row rl, features f0..f0+3
  const int row = rl;
  const int grow = rowbase + row;
  {
    float4 wbv[2];
    wbv[0] = *(const float4*)(doutb + w * 32 + h4);
    wbv[1] = *(const float4*)(doutb + w * 32 + 16 + h4);
    float s = 0.f, ss = 0.f;
#pragma unroll
    for (int fn = 0; fn < 2; ++fn) {
      const int f0 = w * 32 + fn * 16 + h4;
      const ushort4 rr = *(const ushort4*)(hV1b + (((size_t)grow) << 7) + f0);
      const float x0 = acc2[fn][0] + wbv[fn].x + bf2f(rr.x);
      const float x1 = acc2[fn][1] + wbv[fn].y + bf2f(rr.y);
      const float x2 = acc2[fn][2] + wbv[fn].z + bf2f(rr.z);
      const float x3 = acc2[fn][3] + wbv[fn].w + bf2f(rr.w);
      acc2[fn] = (f32x4){x0, x1, x2, x3};
      s += x0 + x1 + x2 + x3;
      ss += x0 * x0 + x1 * x1 + x2 * x2 + x3 * x3;
    }
    s += __shfl_xor(s, 16); s += __shfl_xor(s, 32);
    ss += __shfl_xor(ss, 16); ss += __shfl_xor(ss, 32);
    if (lane < 16) { sStat[row][0][w] = s; sStat[row][1][w] = ss; }
  }
  __syncthreads();
  {
    const float sum = sStat[row][0][0] + sStat[row][0][1] + sStat[row][0][2] + sStat[row][0][3];
    const float ssq = sStat[row][1][0] + sStat[row][1][1] + sStat[row][1][2] + sStat[row][1][3];
    const float mean = sum * (1.0f / 128.0f);
    const float inv = rsqrtf(ssq * (1.0f / 128.0f) - mean * mean + EPS_);
    const float mv = maskV[grow];
#pragma unroll
    for (int fn = 0; fn < 2; ++fn) {
      const int f0 = w * 32 + fn * 16 + h4;
      const float4 gv = *(const float4*)(n2g + f0);
      const float4 bv = *(const float4*)(n2b + f0);
      const float y0 = (gv.x * (acc2[fn][0] - mean) * inv + bv.x) * mv;
      const float y1 = (gv.y * (acc2[fn][1] - mean) * inv + bv.y) * mv;
      const float y2 = (gv.z * (acc2[fn][2] - mean) * inv + bv.z) * mv;
      const float y3 = (gv.w * (acc2[fn][3] - mean) * inv + bv.w) * mv;
      *(float4*)(outV + (((size_t)grow) << 7) + f0) = make_float4(y0, y1, y2, y3);
      uint2 o; o.x = pkbf(y0, y1); o.y = pkbf(y2, y3);
      *(uint2*)(hV2c + (((size_t)grow) << 7) + f0) = o;
    }
  }
}

// ---- k3: edge MLP + residual(stash) + LN3 -> outE (R7-passing structure) ----
__global__ __launch_bounds__(256, 4) void k3(
    const int* __restrict__ Eidx, const unsigned short* __restrict__ wc,
    const unsigned short* __restrict__ Y2c, const unsigned short* __restrict__ Y2n,
    const float* __restrict__ W11b, const float* __restrict__ W12b,
    const float* __restrict__ W13b, const float* __restrict__ n3g,
    const float* __restrict__ n3b, float* __restrict__ outE) {
  __shared__ __align__(16) unsigned short sE[64 * LDA];  // hE bf16 (stays intact for residual)
  __shared__ __align__(16) unsigned short sG[64 * LDA];  // Yn gather -> X1 -> X2
  __shared__ unsigned short sYc[2 * 128];
  __shared__ float sStat[64][2][4];

  const int tid = threadIdx.x;
  const int lane = tid & 63;
  const int w = tid >> 6;
  const int rl = lane & 15;
  const int h4 = (lane >> 4) << 2;
  const int bid = (blockIdx.x & 7) * 1024 + (blockIdx.x >> 3);
  const int v0 = bid << 1;
  const int b = v0 >> 11;
  const int n0 = v0 & (N_ - 1);
  const int bBase = b * N_;

  const unsigned short* W11c = wc + 81920;
  const unsigned short* W12c = wc + 131072;
  const unsigned short* W13c = wc + 147456;

  // stage hE bf16 rows from outE second halves (stash written by k1)
  for (int t = tid; t < 1024; t += 256) {
    const int r = t >> 4, seg = t & 15;
    const int g = r >> 5;
    int kk = r & 31; if (kk >= K_) kk = K_ - 1;
    const size_t e = (size_t)(bBase + n0 + g) * K_ + kk;
    *(short8*)(sE + r * LDA + seg * 8) =
        *(const short8*)((const unsigned short*)(outE + (e << 7)) + 128 + seg * 8);
  }
  // stage gathered Y2n rows
  for (int t = tid; t < 1024; t += 256) {
    const int r = t >> 4, seg = t & 15;
    const int g = r >> 5;
    int kk = r & 31; if (kk >= K_) kk = K_ - 1;
    const int j = Eidx[(bBase + n0 + g) * K_ + kk];
    *(short8*)(sG + r * LDA + seg * 8) =
        *(const short8*)(Y2n + (size_t)(bBase + j) * 128 + seg * 8);
  }
  {
    const int g = tid >> 7, c = tid & 127;
    sYc[g * 128 + c] = Y2c[(size_t)(bBase + n0 + g) * 128 + c];
  }
  __syncthreads();

  f32x4 acc[4][2];
  ZERO42(acc)
  gemm64<384, 2>(sE, W11c + 256, lane, w * 32, acc);

#pragma unroll
  for (int n = 0; n < 2; ++n) {
    const int f = w * 32 + n * 16 + rl;
    const float bb = W11b[f];
#pragma unroll
    for (int m = 0; m < 4; ++m)
#pragma unroll
      for (int i = 0; i < 4; ++i) {
        const int e = m * 16 + h4 + i;
        const float x = acc[m][n][i] + bb + bf2f(sYc[(e >> 5) * 128 + f]) + bf2f(sG[e * LDA + f]);
        sG[e * LDA + f] = f2bf(gelu_t(x));
      }
  }
  __syncthreads();

  f32x4 acc2[4][2];
  ZERO42(acc2)
  gemm64<128, 2>(sG, W12c, lane, w * 32, acc2);
  __syncthreads();
#pragma unroll
  for (int n = 0; n < 2; ++n) {
    const int f = w * 32 + n * 16 + rl;
    const float bb = W12b[f];
#pragma unroll
    for (int m = 0; m < 4; ++m)
#pragma unroll
      for (int i = 0; i < 4; ++i) {
        const int e = m * 16 + h4 + i;
        sG[e * LDA + f] = f2bf(gelu_t(acc2[m][n][i] + bb));
      }
  }
  __syncthreads();

  f32x4 acc3[4][2];
  ZERO42(acc3)
  gemm64<128, 2>(sG, W13c, lane, w * 32, acc3);

  // epilogue: x = msg + b + hE(bf16 from sE); LN3 with 4-wave partials
  float gc[2], bc[2], wb[2];
#pragma unroll
  for (int n = 0; n < 2; ++n) {
    const int f = w * 32 + n * 16 + rl;
    gc[n] = n3g[f]; bc[n] = n3b[f]; wb[n] = W13b[f];
  }
#pragma unroll
  for (int m = 0; m < 4; ++m)
#pragma unroll
    for (int i = 0; i < 4; ++i) {
      const int e = m * 16 + h4 + i;
      float s = 0.f, ss = 0.f;
#pragma unroll
      for (int n = 0; n < 2; ++n) {
        const int f = w * 32 + n * 16 + rl;
        const float x = acc3[m][n][i] + wb[n] + bf2f(sE[e * LDA + f]);
        acc3[m][n][i] = x;
        s += x; ss += x * x;
      }
#pragma unroll
      for (int o = 1; o <= 8; o <<= 1) { s += __shfl_xor(s, o); ss += __shfl_xor(ss, o); }
      if (rl == 0) { sStat[e][0][w] = s; sStat[e][1][w] = ss; }
    }
  __syncthreads();
#pragma unroll
  for (int m = 0; m < 4; ++m)
#pragma unroll
    for (int i = 0; i < 4; ++i) {
      const int e = m * 16 + h4 + i;
      const int g = e >> 5, kk = e & 31;
      if (kk >= K_) continue;
      const float sum = sStat[e][0][0] + sStat[e][0][1] + sStat[e][0][2] + sStat[e][0][3];
      const float ssq = sStat[e][1][0] + sStat[e][1][1] + sStat[e][1][2] + sStat[e][1][3];
      const float mean = sum * (1.0f / 128.0f);
      const float inv = rsqrtf(ssq * (1.0f / 128.0f) - mean * mean + EPS_);
      float* dst = outE + (((size_t)((bBase + n0 + g) * K_ + kk)) << 7) + w * 32 + rl;
#pragma unroll
      for (int n = 0; n < 2; ++n)
        dst[n * 16] = gc[n] * (acc3[m][n][i] - mean) * inv + bc[n];
    }
}

extern "C" void kernel_launch(void* const* d_in, const int* in_sizes, int n_in,
                              void* d_out, int out_size, void* d_ws, size_t ws_size,
                              hipStream_t stream) {
  const float* hV = (const float*)d_in[0];
  const float* hE = (const float*)d_in[1];
  const int* Eidx = (const int*)d_in[2];
  const float* maskV = (const float*)d_in[3];
  const float* mattend = (const float*)d_in[4];
  const float* W1w = (const float*)d_in[5];   const float* W1b = (const float*)d_in[6];
  const float* W2w = (const float*)d_in[7];   const float* W2b = (const float*)d_in[8];
  const float* W3w = (const float*)d_in[9];   const float* W3b = (const float*)d_in[10];
  const float* W11w = (const float*)d_in[11]; const float* W11b = (const float*)d_in[12];
  const float* W12w = (const float*)d_in[13]; const float* W12b = (const float*)d_in[14];
  const float* W13w = (const float*)d_in[15]; const float* W13b = (const float*)d_in[16];
  const float* n1g = (const float*)d_in[17];  const float* n1b = (const float*)d_in[18];
  const float* n2g = (const float*)d_in[19];  const float* n2b = (const float*)d_in[20];
  const float* n3g = (const float*)d_in[21];  const float* n3b = (const float*)d_in[22];
  const float* dinw = (const float*)d_in[23]; const float* dinb = (const float*)d_in[24];
  const float* doutw = (const float*)d_in[25]; const float* doutb = (const float*)d_in[26];

  // ws layout (bytes), peak == proven 13,172,736:
  //   [0, 589824)          wc  (bf16 weights)
  //   [589824, 8978432)    Region1: Y1 (k1 phase) -> hV2c (1st half) + Y2c (2nd half)
  //   [8978432, 13172736)  Region2: hV1b (k1/k2) -> Y2n (k3 phase)
  unsigned short* wc   = (unsigned short*)d_ws;
  unsigned short* R1   = wc + 294912;
  unsigned short* R2   = R1 + 4194304;
  unsigned short* Y1   = R1;            // [BN][256] bf16
  unsigned short* hV1b = R2;            // [BN][128] bf16
  unsigned short* hV2c = R1;            // [BN][128] bf16 (Y1 dead after k1)
  unsigned short* Y2c  = R1 + 2097152;  // [BN][128] bf16
  unsigned short* Y2n  = R2;            // [BN][128] bf16 (hV1b dead after k2)

  float* outV = (float*)d_out;
  float* outE = outV + (size_t)B_ * N_ * H_;

  prep<<<1152, 256, 0, stream>>>(W1w, W2w, W3w, W11w, W12w, W13w, dinw, doutw, wc);
  preY<true, false><<<256, 256, 0, stream>>>(hV, wc, Y1, Y1);
  k1<<<8192, 256, 0, stream>>>(hV, hE, Eidx, mattend, wc, Y1,
                               W1b, W2b, W3b, n1g, n1b, hV1b, outE);
  k2<<<1024, 256, 0, stream>>>(hV1b, wc, dinb, doutb, n2g, n2b, maskV, outV, hV2c);
  preY<false, true><<<256, 256, 0, stream>>>(hV2c, wc + 81920, Y2c, Y2n);
  k3<<<8192, 256, 0, stream>>>(Eidx, wc, Y2c, Y2n,
                               W11b, W12b, W13b, n3g, n3b, outE);
}